// Round 5
// baseline (123.103 us; speedup 1.0000x reference)
//
#include <hip/hip_runtime.h>
#include <limits.h>

// Problem constants (fixed by setup_inputs in the reference)
#define BB 2
#define SS 4096
#define DD 512
#define VV 32000
#define FE_START 5
#define FE_LEN 3062
#define ADV_LEN 64
#define ML 995
#define MR 2003
#define KP (2 * MR + 1)          // 4007
#define PHALF (KP / 2)           // 2003
#define LEFT_PAD (MR - ML)       // 1008
#define PARAM_LEN (ML + MR + 1)  // 2999

// Native clang vector type: __builtin_nontemporal_store accepts these,
// unlike HIP's struct-based float4.
typedef float floatx4 __attribute__((ext_vector_type(4)));

// pk[i] = param[KP-1-LEFT_PAD-i] for valid range, else 0.
// Nonzero param[j] <=> tap at offset (995 - j) with weight param[j].
// ms = p - argmax(pk==1.0) = jmax - 995 where jmax = LAST j with param[j]==1.0
// (argmax picks first/smallest i, which maps to largest j). No 1.0 -> ms=PHALF.

// Workspace (int view):
//  meta[0] = nnz, meta[1] = ms, meta[2+b] = a0[b], meta[4] = identity-conv flag
//  meta[16+2k] = tap offset; meta[16+2k+1] = float weight bits

__global__ void ABS_meta_kernel(const unsigned char* __restrict__ mask_bytes,
                                const float* __restrict__ param,
                                int* __restrict__ meta,
                                int tap_cap) {
    __shared__ int s_nnz;
    __shared__ int s_jmax;    // last j with param[j]==1.0
    __shared__ int s_firstb;  // first nonzero byte in first BB*SS bytes
    __shared__ int s_layout;  // 1 = byte bools, 4 = int32
    __shared__ int s_off0;    // offset of tap slot 0
    __shared__ float s_w0;    // weight of tap slot 0
    __shared__ int s_a0b[BB]; // byte-layout candidates
    __shared__ int s_a0i[BB]; // int32-layout candidates

    const int tid = threadIdx.x;
    const int nt = blockDim.x;
    if (tid == 0) {
        s_nnz = 0; s_jmax = -1; s_firstb = INT_MAX;
        s_off0 = INT_MAX; s_w0 = 0.0f;
    }
    if (tid < BB) { s_a0b[tid] = INT_MAX; s_a0i[tid] = INT_MAX; }
    __syncthreads();

    // ---- pass 1: first BB*SS bytes as ulongs (safe under both layouts).
    // All loads independent -> one memory latency.
    const unsigned long long* m8 = (const unsigned long long*)mask_bytes;
    for (int i = tid; i < (BB * SS) / 8; i += nt) {
        unsigned long long w = m8[i];
        if (w) {
            int fb = i * 8 + (__ffsll((long long)w) - 1) / 8;
            atomicMin(&s_firstb, fb);
            // byte-layout interpretation: each nonzero byte is a True
            #pragma unroll
            for (int k = 0; k < 8; ++k) {
                if ((w >> (8 * k)) & 0xffull) {
                    int pos = i * 8 + k;
                    atomicMin(&s_a0b[pos / SS], pos % SS);
                }
            }
            // int32-layout interpretation: ints 2i, 2i+1
            if ((unsigned int)w) {
                int pos = 2 * i;
                atomicMin(&s_a0i[pos / SS], pos % SS);
            }
            if ((unsigned int)(w >> 32)) {
                int pos = 2 * i + 1;
                atomicMin(&s_a0i[pos / SS], pos % SS);
            }
        }
    }

    // ---- param taps (independent of mask scan, same load phase)
    for (int j = tid; j < PARAM_LEN; j += nt) {
        float w = param[j];
        if (w != 0.0f) {
            int slot = atomicAdd(&s_nnz, 1);
            if (slot < tap_cap) {
                int* tp = meta + 16 + 2 * slot;
                tp[0] = 995 - j;
                ((float*)tp)[1] = w;
            }
            if (slot == 0) { s_off0 = 995 - j; s_w0 = w; }
        }
        if (w == 1.0f) atomicMax(&s_jmax, j);
    }
    __syncthreads();

    // ---- layout decision (one dependent byte probe)
    if (tid == 0) {
        int f = s_firstb;
        int layout = 1;
        if (f != INT_MAX) {
            // adv_len >= 2: byte bools have consecutive nonzero bytes;
            // int32 LE value 1 has a zero byte at f+1.
            layout = (f + 1 < BB * SS && mask_bytes[f + 1] != 0) ? 1 : 4;
        }
        s_layout = layout;
    }
    __syncthreads();

    // ---- pass 2 only if int32 layout: remaining ints (bytes BB*SS..4*BB*SS)
    if (s_layout == 4) {
        for (int i = (BB * SS) / 8 + tid; i < (4 * BB * SS) / 8; i += nt) {
            unsigned long long w = m8[i];
            if (w) {
                if ((unsigned int)w) {
                    int pos = 2 * i;
                    atomicMin(&s_a0i[pos / SS], pos % SS);
                }
                if ((unsigned int)(w >> 32)) {
                    int pos = 2 * i + 1;
                    atomicMin(&s_a0i[pos / SS], pos % SS);
                }
            }
        }
        __syncthreads();
    }

    if (tid == 0) {
        meta[0] = (s_nnz < tap_cap) ? s_nnz : tap_cap;
        meta[1] = (s_jmax >= 0) ? (s_jmax - 995) : PHALF;  // ms
        for (int b = 0; b < BB; ++b) {
            int a0 = (s_layout == 1) ? s_a0b[b] : s_a0i[b];
            meta[2 + b] = (a0 == INT_MAX) ? 0 : a0;
        }
        // identity-conv fast path: exactly one tap, offset 0, weight 1.0
        meta[4] = (s_nnz == 1 && s_off0 == 0 && s_w0 == 1.0f) ? 1 : 0;
    }
}

// One block per (b, t); 128 threads x float4 = 512 floats = one D row.
__global__ void __launch_bounds__(128)
ABS_embed_ids_kernel(const int* __restrict__ ids,
                     const float* __restrict__ emb,   // V x D
                     const int* __restrict__ meta,
                     float* __restrict__ out) {
    const int bt = blockIdx.x;            // 0 .. BB*SS-1
    const int b = bt / SS;
    const int t = bt % SS;
    const int d4 = threadIdx.x;           // float4 index within the row

    floatx4* out4 = (floatx4*)(out + (size_t)bt * DD);
    floatx4 res;

    const bool in_fe = (t >= FE_START) && (t < FE_START + FE_LEN);
    bool copy_path = !in_fe;
    if (in_fe && meta[4]) copy_path = true;  // identity conv -> plain copy

    if (copy_path) {
        const int id = ids[bt];
        res = ((const floatx4*)(emb + (size_t)id * DD))[d4];
    } else {
        const int tt = t - FE_START;
        const int nnz = meta[0];
        floatx4 acc = (floatx4)(0.f);
        for (int k = 0; k < nnz; ++k) {
            const int* tp = meta + 16 + 2 * k;
            const int off = tp[0];
            const float w = ((const float*)tp)[1];
            const int s = tt + off;
            if (s >= 0 && s < FE_LEN) {
                const int id = ids[b * SS + FE_START + s];
                const floatx4 v = ((const floatx4*)(emb + (size_t)id * DD))[d4];
                acc += w * v;
            }
        }
        res = acc;
    }

    // Output is write-once / never re-read: keep it out of L2 so the
    // emb-row gather keeps its L2 residency.
    __builtin_nontemporal_store(res, &out4[d4]);

    // Fused out_ids: one element per (b, t), written as float
    if (threadIdx.x == 0) {
        const int ms = meta[1];
        const int a0 = meta[2 + b];
        const int ns = a0 + ms;
        const int j = t;
        int outid;
        if (j >= ns && j < ns + ADV_LEN) {
            outid = ids[b * SS + a0 + (j - ns)];
        } else {
            int k = (j < ns) ? j : (j - ADV_LEN);
            k = min(max(k, 0), SS - ADV_LEN - 1);
            const int src = k + ((k >= a0) ? ADV_LEN : 0);
            outid = ids[b * SS + src];
        }
        __builtin_nontemporal_store((float)outid,
                                    out + (size_t)BB * SS * DD + bt);
    }
}

extern "C" void kernel_launch(void* const* d_in, const int* in_sizes, int n_in,
                              void* d_out, int out_size, void* d_ws, size_t ws_size,
                              hipStream_t stream) {
    const int* ids = (const int*)d_in[0];
    const unsigned char* mask = (const unsigned char*)d_in[1];
    const float* param = (const float*)d_in[2];
    const float* emb = (const float*)d_in[3];
    float* out = (float*)d_out;
    int* meta = (int*)d_ws;

    int tap_cap = (int)((ws_size > 128 ? ws_size - 64 : 64) / 8);
    if (tap_cap > KP) tap_cap = KP;

    ABS_meta_kernel<<<1, 1024, 0, stream>>>(mask, param, meta, tap_cap);
    ABS_embed_ids_kernel<<<BB * SS, 128, 0, stream>>>(ids, emb, meta, out);
}

// Round 6
// 122.538 us; speedup vs baseline: 1.0046x; 1.0046x over previous
//
#include <hip/hip_runtime.h>
#include <limits.h>

// Problem constants (fixed by setup_inputs in the reference)
#define BB 2
#define SS 4096
#define DD 512
#define VV 32000
#define FE_START 5
#define FE_LEN 3062
#define ADV_LEN 64
#define ML 995
#define MR 2003
#define KP (2 * MR + 1)          // 4007
#define PHALF (KP / 2)           // 2003
#define PARAM_LEN (ML + MR + 1)  // 2999

#define ROWS 4                   // rows (b,t) per block
#define TPB 256                  // 4 rows x 64 lanes
#define TAP_CAP 128              // shared tap list capacity

// Native clang vector type: __builtin_nontemporal_store accepts these,
// unlike HIP's struct-based float4.
typedef float floatx4 __attribute__((ext_vector_type(4)));

// Single fused kernel. Each block recomputes the (tiny) metadata itself:
// param (12 KB) and mask (4-16 KB) are L2-resident after the first touch,
// so 2048 blocks re-reading them costs ~1 us aggregate at L2 BW — cheaper
// than a second serialized kernel launch (~10-20 us of launch + gap).
//
// Metadata semantics (same as the previous two-kernel version, verified
// absmax=0.0 in round 5):
//  - Nonzero param[j] <=> conv tap at offset (995 - j) with weight param[j].
//  - ms = jmax - 995 where jmax = LAST j with param[j]==1.0; none -> PHALF.
//  - a0[b] = index of first True in suffix_mask[b]; layout of the mask
//    buffer (byte bools vs int32) is auto-detected: byte bools have
//    ADV_LEN>=2 consecutive nonzero bytes, int32 LE value 1 has a zero
//    byte right after its LSB.
__global__ void __launch_bounds__(TPB)
ABS_fused_kernel(const int* __restrict__ ids,
                 const unsigned char* __restrict__ mask_bytes,
                 const float* __restrict__ param,
                 const float* __restrict__ emb,   // V x D
                 float* __restrict__ out) {
    __shared__ int s_nnz;
    __shared__ int s_jmax;
    __shared__ int s_a0b;     // byte-layout first-True (batch-relative)
    __shared__ int s_a0i;     // int32-layout first-True (batch-relative)
    __shared__ int s_layout;  // 1 = byte bools, 4 = int32
    __shared__ int s_toff[TAP_CAP];
    __shared__ float s_tw[TAP_CAP];

    const int tid = threadIdx.x;
    const int blocks_per_b = SS / ROWS;        // 1024
    const int b = blockIdx.x / blocks_per_b;   // 0..BB-1 (pow2 -> shift)
    const int t0 = (blockIdx.x % blocks_per_b) * ROWS;

    if (tid == 0) { s_nnz = 0; s_jmax = -1; s_a0b = INT_MAX; s_a0i = INT_MAX; }
    __syncthreads();

    // ---- param scan (12 KB, L2-resident): taps + jmax
    for (int j = tid; j < PARAM_LEN; j += TPB) {
        const float w = param[j];
        if (w != 0.0f) {
            const int slot = atomicAdd(&s_nnz, 1);
            if (slot < TAP_CAP) { s_toff[slot] = 995 - j; s_tw[slot] = w; }
        }
        if (w == 1.0f) atomicMax(&s_jmax, j);
    }

    // ---- byte-layout scan of this batch (4 KB as 512 ulongs)
    const unsigned long long* m8 = (const unsigned long long*)mask_bytes;
    for (int i = tid; i < SS / 8; i += TPB) {
        const unsigned long long w = m8[(size_t)b * (SS / 8) + i];
        if (w) {
            const int byteidx = i * 8 + (__ffsll((long long)w) - 1) / 8;
            atomicMin(&s_a0b, byteidx);
        }
    }
    __syncthreads();

    // ---- layout decision (one dependent byte probe)
    if (tid == 0) {
        int layout;
        if (s_a0b == INT_MAX) {
            layout = 4;  // no trues visible in byte view of this batch
        } else {
            const int fb = b * SS + s_a0b;
            // adv_len >= 2: byte bools -> next byte nonzero; int32 LE 1 -> 0.
            layout = (mask_bytes[fb + 1] != 0) ? 1 : 4;
        }
        s_layout = layout;
    }
    __syncthreads();

    // ---- int32-layout scan only if needed (16 KB as 2048 ulongs)
    if (s_layout == 4) {
        for (int i = tid; i < SS / 2; i += TPB) {
            const unsigned long long w = m8[(size_t)b * (SS / 2) + i];
            if (w) {
                if ((unsigned int)w)         atomicMin(&s_a0i, 2 * i);
                if ((unsigned int)(w >> 32)) atomicMin(&s_a0i, 2 * i + 1);
            }
        }
        __syncthreads();
    }

    const int nnz = s_nnz;
    const int ms = (s_jmax >= 0) ? (s_jmax - 995) : PHALF;
    int a0 = (s_layout == 1) ? s_a0b : s_a0i;
    if (a0 == INT_MAX) a0 = 0;
    const bool ident = (nnz == 1) && (s_toff[0] == 0) && (s_tw[0] == 1.0f);

    // ---- compute phase: ROWS rows x 64 lanes x 8 floats (32 B/thread)
    const int row = tid >> 6;   // 0..3
    const int lane = tid & 63;  // 0..63
    const int t = t0 + row;
    const int bt = b * SS + t;
    const int f4a = 2 * lane, f4b = 2 * lane + 1;

    floatx4 ra, rb;
    const bool in_fe = (t >= FE_START) && (t < FE_START + FE_LEN);

    if (!in_fe || ident) {
        const int id = ids[bt];
        const floatx4* src = (const floatx4*)(emb + (size_t)id * DD);
        ra = src[f4a];
        rb = src[f4b];
    } else {
        const int tt = t - FE_START;
        floatx4 aa = (floatx4)(0.f), ab = (floatx4)(0.f);
        if (nnz <= TAP_CAP) {
            for (int k = 0; k < nnz; ++k) {
                const int s = tt + s_toff[k];
                const float w = s_tw[k];
                if (s >= 0 && s < FE_LEN) {
                    const int id = ids[b * SS + FE_START + s];
                    const floatx4* src = (const floatx4*)(emb + (size_t)id * DD);
                    aa += w * src[f4a];
                    ab += w * src[f4b];
                }
            }
        } else {
            // Correct-but-slow fallback (never taken with this input):
            // stream all taps straight from L2-resident param.
            for (int j = 0; j < PARAM_LEN; ++j) {
                const float w = param[j];
                if (w != 0.0f) {
                    const int s = tt + (995 - j);
                    if (s >= 0 && s < FE_LEN) {
                        const int id = ids[b * SS + FE_START + s];
                        const floatx4* src = (const floatx4*)(emb + (size_t)id * DD);
                        aa += w * src[f4a];
                        ab += w * src[f4b];
                    }
                }
            }
        }
        ra = aa;
        rb = ab;
    }

    // Output is write-once / never re-read: non-temporal keeps L2 for the
    // emb-row gather.
    floatx4* out4 = (floatx4*)(out + (size_t)bt * DD);
    __builtin_nontemporal_store(ra, &out4[f4a]);
    __builtin_nontemporal_store(rb, &out4[f4b]);

    // ---- fused out_ids: ROWS elements per block, threads 0..ROWS-1
    if (tid < ROWS) {
        const int tj = t0 + tid;
        const int btj = b * SS + tj;
        const int ns = a0 + ms;
        int outid;
        if (tj >= ns && tj < ns + ADV_LEN) {
            outid = ids[b * SS + a0 + (tj - ns)];
        } else {
            int k = (tj < ns) ? tj : (tj - ADV_LEN);
            k = min(max(k, 0), SS - ADV_LEN - 1);
            const int src = k + ((k >= a0) ? ADV_LEN : 0);
            outid = ids[b * SS + src];
        }
        __builtin_nontemporal_store((float)outid,
                                    out + (size_t)BB * SS * DD + btj);
    }
}

extern "C" void kernel_launch(void* const* d_in, const int* in_sizes, int n_in,
                              void* d_out, int out_size, void* d_ws, size_t ws_size,
                              hipStream_t stream) {
    const int* ids = (const int*)d_in[0];
    const unsigned char* mask = (const unsigned char*)d_in[1];
    const float* param = (const float*)d_in[2];
    const float* emb = (const float*)d_in[3];
    float* out = (float*)d_out;
    (void)d_ws; (void)ws_size;  // no workspace needed anymore

    ABS_fused_kernel<<<BB * (SS / ROWS), TPB, 0, stream>>>(ids, mask, param,
                                                           emb, out);
}